// Round 7
// baseline (82.057 us; speedup 1.0000x reference)
//
#include <hip/hip_runtime.h>
#include <stdint.h>

#define N_TOT 10647
#define MAXW  167        // ceil(10647/64)
#define NB    42         // ceil(10647/256)
#define NBD   167        // ceil(10647/64) decode blocks
#define NCLS  80
#define ECAP  (1 << 20)  // edge buffer cap (4 MB); expected E ~ 1e3-1e4

typedef unsigned long long ull;

// YOLOv3 COCO anchors, grouped by head: [0..2]=13x13, [3..5]=26x26, [6..8]=52x52
__constant__ float c_aw[9] = {116.f,156.f,373.f, 30.f,62.f,59.f, 10.f,16.f,33.f};
__constant__ float c_ah[9] = { 90.f,198.f,326.f, 61.f,45.f,119.f, 13.f,30.f,23.f};

__device__ __forceinline__ float sigmoidf_(float x) { return 1.0f / (1.0f + expf(-x)); }

// 4 threads per box: sub s (=tid>>6) scans classes [20s,20s+20); lane (=tid&63)
// picks the box. Strict '>' everywhere preserves jnp.argmax first-max-wins.
// Block 0 thread 0 also zeroes dV (consumed two kernels later; stream-ordered).
__global__ void __launch_bounds__(256)
decode_kernel(const float* __restrict__ p0, const float* __restrict__ p1,
              const float* __restrict__ p2,
              float* __restrict__ box, float* __restrict__ conf,
              float* __restrict__ score, int* __restrict__ cls,
              int* __restrict__ dV)
{
    __shared__ float sbest[4][64];
    __shared__ int   sbi[4][64];
    if (blockIdx.x == 0 && threadIdx.x == 0) *dV = 0;
    int sub  = threadIdx.x >> 6;
    int lane = threadIdx.x & 63;
    int n = blockIdx.x * 64 + lane;
    bool inb = (n < N_TOT);
    const float* p; int H, base, lvl; float stride;
    int nn = inb ? n : 0;
    if (nn < 507)       { p = p0; H = 13; base = 0;    stride = 32.f; lvl = 0; }
    else if (nn < 2535) { p = p1; H = 26; base = 507;  stride = 16.f; lvl = 1; }
    else                { p = p2; H = 52; base = 2535; stride = 8.f;  lvl = 2; }
    int m   = nn - base;
    int HW  = H * H;
    int a   = m / HW;
    int rem = m - a * HW;
    const float* q = p + (size_t)(a * 85) * HW + rem;
    float best = -3.4e38f; int bi = 20 * sub;
    if (inb) {
        int c0 = 20 * sub;
        #pragma unroll 5
        for (int c = c0; c < c0 + 20; ++c) {
            float v = q[(size_t)(5 + c) * HW];
            if (v > best) { best = v; bi = c; }
        }
    }
    sbest[sub][lane] = best;
    sbi[sub][lane]   = bi;
    __syncthreads();
    if (sub == 0 && inb) {
        float b0 = sbest[0][lane]; int i0 = sbi[0][lane];
        #pragma unroll
        for (int s = 1; s < 4; ++s) {
            float bs = sbest[s][lane];
            if (bs > b0) { b0 = bs; i0 = sbi[s][lane]; }
        }
        int gy = rem / H;
        int gx = rem - gy * H;
        float tx = q[0];
        float ty = q[(size_t)HW];
        float tw = q[(size_t)2*HW];
        float th = q[(size_t)3*HW];
        float tc = q[(size_t)4*HW];
        float cx = (sigmoidf_(tx) + (float)gx) * stride;
        float cy = (sigmoidf_(ty) + (float)gy) * stride;
        // exp(t)*(anchor/stride)*stride == exp(t)*anchor exactly (stride pow2)
        float bw = expf(tw) * c_aw[lvl*3 + a];
        float bh = expf(th) * c_ah[lvl*3 + a];
        float cf = sigmoidf_(tc);
        box[n*4+0] = cx; box[n*4+1] = cy; box[n*4+2] = bw; box[n*4+3] = bh;
        conf[n] = cf;
        cls[n]  = i0;
        score[n] = (cf >= 0.5f) ? cf : -1.0f;
    }
}

// Partial stable-descending rank: block (bx,by) compares i-tile bx against
// j-tile by (staged in LDS). rank42[by*N + i] = partial count. No atomics.
__global__ void __launch_bounds__(256)
rank_partial_kernel(const float* __restrict__ score, int* __restrict__ rank42)
{
    __shared__ float tile[256];
    int tid = threadIdx.x;
    int i   = blockIdx.x * 256 + tid;
    int j0  = blockIdx.y * 256;
    int jj  = j0 + tid;
    tile[tid] = (jj < N_TOT) ? score[jj] : -2.0f;   // sentinel < all scores
    __syncthreads();
    float si = (i < N_TOT) ? score[i] : -2.0f;
    if (i >= N_TOT || si < 0.0f) return;            // invalid i: partial unused
    int r = 0;
    #pragma unroll 8
    for (int t = 0; t < 256; ++t) {
        float sj = tile[t];
        r += (sj > si || (sj == si && (j0 + t) < i)) ? 1 : 0;
    }
    rank42[(size_t)blockIdx.y * N_TOT + i] = r;
}

// Sum partial ranks, scatter order[r]=i, gather corner/area/class arrays,
// and count valid boxes into dV (zeroed by decode).
__global__ void __launch_bounds__(256)
scatter_gather_kernel(const float* __restrict__ box, const int* __restrict__ cls,
                      const float* __restrict__ score, const int* __restrict__ rank42,
                      int* __restrict__ order,
                      float* __restrict__ sx1, float* __restrict__ sy1,
                      float* __restrict__ sx2, float* __restrict__ sy2,
                      float* __restrict__ sarea, int* __restrict__ scls,
                      int* __restrict__ dV)
{
    int i = blockIdx.x * blockDim.x + threadIdx.x;
    if (i >= N_TOT) return;
    if (score[i] < 0.0f) return;
    atomicAdd(dV, 1);
    int r = 0;
    #pragma unroll 6
    for (int s = 0; s < NB; ++s) r += rank42[(size_t)s * N_TOT + i];
    order[r] = i;
    float cx = box[i*4+0], cy = box[i*4+1], w = box[i*4+2], h = box[i*4+3];
    float hw = w * 0.5f, hh = h * 0.5f;
    sx1[r] = cx - hw; sy1[r] = cy - hh;
    sx2[r] = cx + hw; sy2[r] = cy + hh;
    sarea[r] = w * h;
    scls[r]  = cls[i];
}

// One block: zero ecnt, histogram scls, 81-entry prefix (coff[80]=V), then
// bucket every sorted rank r into class_idx[coff[c]+pos] via LDS cursors.
// Bucket order is irrelevant: edge direction is decided by rank comparison.
__global__ void __launch_bounds__(256)
class_fill_kernel(const int* __restrict__ scls, const int* __restrict__ dV,
                  int* __restrict__ coff, int* __restrict__ class_idx,
                  int* __restrict__ ecnt)
{
    __shared__ int hist[NCLS];
    __shared__ int loff[NCLS];
    __shared__ int lcur[NCLS];
    int tid = threadIdx.x;
    if (tid == 0) *ecnt = 0;
    if (tid < NCLS) { hist[tid] = 0; lcur[tid] = 0; }
    __syncthreads();
    int V = *dV;
    for (int r = tid; r < V; r += 256) atomicAdd(&hist[scls[r]], 1);
    __syncthreads();
    if (tid == 0) {
        int off = 0;
        for (int c = 0; c < NCLS; ++c) { loff[c] = off; off += hist[c]; }
    }
    __syncthreads();
    for (int r = tid; r < V; r += 256) {
        int c = scls[r];
        int pos = atomicAdd(&lcur[c], 1);
        class_idx[loff[c] + pos] = r;
    }
    if (tid < NCLS) coff[tid] = loff[tid];
    if (tid == 0) coff[NCLS] = V;
}

// Per-class all-pairs IoU (one block per class, tiled). Same class by
// construction; emit packed edge (i<<16|j) with j=min(ra,rb) < i=max(ra,rb).
__global__ void __launch_bounds__(256)
edge_class_kernel(const float* __restrict__ sx1, const float* __restrict__ sy1,
                  const float* __restrict__ sx2, const float* __restrict__ sy2,
                  const float* __restrict__ sarea,
                  const int* __restrict__ coff, const int* __restrict__ class_idx,
                  uint32_t* __restrict__ edges, int* __restrict__ ecnt)
{
    __shared__ float tx1[256], ty1[256], tx2[256], ty2[256], tar[256];
    __shared__ int   trk[256];
    int c   = blockIdx.x;
    int off = coff[c];
    int n   = coff[c + 1] - off;
    int tid = threadIdx.x;
    for (int abase = 0; abase < n; abase += 256) {
        int a = abase + tid;
        bool ain = (a < n);
        int ra = 0; float ax1=0, ay1=0, ax2=0, ay2=0, aar=0;
        if (ain) {
            ra  = class_idx[off + a];
            ax1 = sx1[ra]; ay1 = sy1[ra];
            ax2 = sx2[ra]; ay2 = sy2[ra];
            aar = sarea[ra];
        }
        for (int bbase = 0; bbase <= abase; bbase += 256) {
            int b = bbase + tid;
            if (b < n) {
                int rb = class_idx[off + b];
                tx1[tid] = sx1[rb]; ty1[tid] = sy1[rb];
                tx2[tid] = sx2[rb]; ty2[tid] = sy2[rb];
                tar[tid] = sarea[rb]; trk[tid] = rb;
            }
            __syncthreads();
            int blim = min(256, n - bbase);
            int tlim = (bbase == abase) ? min(tid, blim) : blim;
            if (ain) {
                for (int t = 0; t < tlim; ++t) {
                    float xx1 = fmaxf(ax1, tx1[t]);
                    float yy1 = fmaxf(ay1, ty1[t]);
                    float xx2 = fminf(ax2, tx2[t]);
                    float yy2 = fminf(ay2, ty2[t]);
                    float w = fmaxf(xx2 - xx1, 0.0f);
                    float h = fmaxf(yy2 - yy1, 0.0f);
                    float inter = w * h;
                    float uni   = aar + tar[t] - inter;
                    float iou   = inter / fmaxf(uni, 1e-9f);
                    if (iou > 0.5f) {
                        int rb = trk[t];
                        uint32_t i = (uint32_t)max(ra, rb);
                        uint32_t j = (uint32_t)min(ra, rb);
                        int pos = atomicAdd(ecnt, 1);
                        if (pos < ECAP) edges[pos] = (i << 16) | j;
                    }
                }
            }
            __syncthreads();
        }
    }
}

// Sparse Jacobi fixpoint for greedy NMS (keep bitmap in LDS) + fused output.
// keep_new[i] = valid[i] & !OR_{edges (j,i)} keep_prev[j].
// Zero-change round == unique fixpoint == greedy solution (induction over the
// index-ordered DAG); depth-d nodes final after d+1 rounds; cap V+2 => exact.
// After convergence the same block writes ALL N_TOT output rows (zeros for
// suppressed/invalid) -- no separate out kernel, no d_out memset.
__global__ void __launch_bounds__(1024)
nms_out_kernel(const uint32_t* __restrict__ edges, const int* __restrict__ ecnt_p,
               const int* __restrict__ dV,
               const float* __restrict__ box, const float* __restrict__ conf,
               const int* __restrict__ cls, const int* __restrict__ order,
               float* __restrict__ out)
{
    __shared__ ull kA[MAXW], kB[MAXW], sup[MAXW];
    __shared__ int changed;
    int tid = threadIdx.x;
    int V = *dV;
    int W = (V + 63) >> 6;
    int E = min(*ecnt_p, ECAP);
    for (int w = tid; w < W; w += 1024) {
        int rem = V - (w << 6);
        kA[w] = (rem >= 64) ? ~0ull : ((1ull << rem) - 1ull);
    }
    ull* cur = kA;
    ull* nxt = kB;
    __syncthreads();
    for (int round = 0; round <= V + 2 && W > 0; ++round) {
        for (int w = tid; w < W; w += 1024) sup[w] = 0ull;
        if (tid == 0) changed = 0;
        __syncthreads();
        for (int e = tid; e < E; e += 1024) {
            uint32_t pk = edges[e];
            int j = pk & 0xFFFF;
            int i = pk >> 16;
            if ((cur[j >> 6] >> (j & 63)) & 1ull)
                atomicOr(&sup[i >> 6], 1ull << (i & 63));
        }
        __syncthreads();
        for (int w = tid; w < W; w += 1024) {
            int rem = V - (w << 6);
            ull valid = (rem >= 64) ? ~0ull : ((1ull << rem) - 1ull);
            ull nk = valid & ~sup[w];
            nxt[w] = nk;
            if (nk != cur[w]) changed = 1;
        }
        __syncthreads();
        int ch = changed;
        __syncthreads();   // everyone reads `changed` before next round resets it
        ull* t = cur; cur = nxt; nxt = t;
        if (!ch) break;
    }
    // fused output: every row written (zeros unless kept)
    for (int r = tid; r < N_TOT; r += 1024) {
        float v0=0.f,v1=0.f,v2=0.f,v3=0.f,v4=0.f,v5=0.f;
        if (r < V && ((cur[r >> 6] >> (r & 63)) & 1ull)) {
            int i = order[r];
            v0 = box[i*4+0]; v1 = box[i*4+1]; v2 = box[i*4+2]; v3 = box[i*4+3];
            v4 = conf[i];    v5 = (float)cls[i];
        }
        out[r*6+0]=v0; out[r*6+1]=v1; out[r*6+2]=v2;
        out[r*6+3]=v3; out[r*6+4]=v4; out[r*6+5]=v5;
    }
}

extern "C" void kernel_launch(void* const* d_in, const int* in_sizes, int n_in,
                              void* d_out, int out_size, void* d_ws, size_t ws_size,
                              hipStream_t stream) {
    const float* p0 = (const float*)d_in[0];
    const float* p1 = (const float*)d_in[1];
    const float* p2 = (const float*)d_in[2];
    float* out = (float*)d_out;
    char* ws = (char*)d_ws;
    const int N = N_TOT;

    float* box   = (float*)ws;          // 4N
    float* conf  = box + 4*N;           // N
    float* score = conf + N;            // N
    float* sx1   = score + N;           // N
    float* sy1   = sx1 + N;             // N
    float* sx2   = sy1 + N;             // N
    float* sy2   = sx2 + N;             // N
    float* sarea = sy2 + N;             // N
    int* cls       = (int*)(sarea + N); // N
    int* order     = cls + N;           // N
    int* scls      = order + N;         // N
    int* class_idx = scls + N;          // N
    int* rank42    = class_idx + N;     // 42N ints = 1.79 MB
    int* dV     = rank42 + (size_t)NB*N; // 1
    int* ecnt   = dV + 1;               // 1
    int* coff   = ecnt + 1;             // 81
    uintptr_t eaddr = ((uintptr_t)(coff + NCLS + 1) + 15) & ~(uintptr_t)15;
    uint32_t* edges = (uint32_t*)eaddr; // ECAP u32 = 4 MB, last in ws

    decode_kernel<<<NBD, 256, 0, stream>>>(p0, p1, p2, box, conf, score, cls, dV);
    rank_partial_kernel<<<dim3(NB, NB), 256, 0, stream>>>(score, rank42);
    scatter_gather_kernel<<<NB, 256, 0, stream>>>(box, cls, score, rank42, order,
                                                  sx1, sy1, sx2, sy2, sarea, scls, dV);
    class_fill_kernel<<<1, 256, 0, stream>>>(scls, dV, coff, class_idx, ecnt);
    edge_class_kernel<<<NCLS, 256, 0, stream>>>(sx1, sy1, sx2, sy2, sarea,
                                                coff, class_idx, edges, ecnt);
    nms_out_kernel<<<1, 1024, 0, stream>>>(edges, ecnt, dV, box, conf, cls, order, out);
}